// Round 10
// baseline (246.545 us; speedup 1.0000x reference)
//
#include <hip/hip_runtime.h>
#include <cstdint>
#include <cstddef>

typedef unsigned int u32;
typedef unsigned short u16;
typedef __attribute__((ext_vector_type(8))) short short8;   // 8 bf16 = 4 VGPRs (MFMA A/B frag)
typedef __attribute__((ext_vector_type(4))) float f32x4;    // MFMA C/D frag

#define S_LEN 1024
#define BATCH 16
#define NHEAD 8
#define DMODEL 512
#define KHD 64
#define NROW (S_LEN * BATCH)          // 16384 GEMM rows

__device__ __forceinline__ u16 f2bf(float f) {
    u32 u = __float_as_uint(f);
    return (u16)((u + 0x7fffu + ((u >> 16) & 1u)) >> 16);   // RTNE
}

__device__ __forceinline__ void gl_lds16(const void* g, void* l) {
    __builtin_amdgcn_global_load_lds(
        (const __attribute__((address_space(1))) void*)(uintptr_t)g,
        (__attribute__((address_space(3))) void*)(uintptr_t)l, 16, 0, 0);
}

// ---------------------------------------------------------------------------
// Unified q/k/v projection, v3. R9 skeleton (gemm_out counted-vmcnt recipe,
// BK=64, 8 waves, bf16 LDS, 2-deep) with BOTH operands reg-staged from fp32:
// B now comes straight from WQ/WK/WV fp32 via the same T14 path as A
// (global_load_dwordx4 -> v_cvt_pk_bf16_f32 (RTNE, bit-identical to f2bf)
// -> swizzled ds_write). This deletes the wcvt dispatch AND its launch gap.
// Per iter: compute(t) -> barrier -> loadA+loadB(t+2) [8 vmem] ->
// vmcnt(8) [tile t+1 landed, t+2 in flight] -> cvt+write A,B(t+1) ->
// lgkmcnt(0) -> barrier. Counted, never drained in steady state.
// T5: s_setprio(1) around the MFMA cluster (counted-vmcnt loop has wave
// role-split -> the regime where setprio measured +21% in learn_hip m218b).
// LDS 64KB -> 2 blocks/CU. W fp32 panels (256KB per (z,by)) are L2-resident
// across the 128 bx-blocks sharing them.
// Decode: bid<1024 -> M1 (z=bid>>9: 0=q,1=k); else M2 (v), bb=r>>5.
// Epilogues: per-head L2 norm; M1 -> [B][H][S][64] (+z*per);
// M2 -> transposed [B][H][64][S] (+2*per).
// ---------------------------------------------------------------------------
__global__ __launch_bounds__(512, 4) void proj_kernel(
    const float* __restrict__ q, const float* __restrict__ k,
    const float* __restrict__ v,
    const float* __restrict__ WQ, const float* __restrict__ WK,
    const float* __restrict__ WV,
    u16* __restrict__ outN)                                    // wsQKV base
{
    __shared__ __align__(16) u16 Alds[2][128 * 64];
    __shared__ __align__(16) u16 Blds[2][128 * 64];

    const int tid  = threadIdx.x;
    const int wave = tid >> 6;          // 0..7
    const int lane = tid & 63;
    const int m16  = lane & 15;
    const int quad = lane >> 4;
    const int wm   = wave >> 1;         // 0..3: 32-row group
    const int wn   = wave & 1;          // 0..1: 64-col half (= head in tile)

    const int bid  = blockIdx.x;
    const bool isM1 = bid < 1024;
    int z, bx, by, bb;
    if (isM1) { z = bid >> 9; by = (bid >> 7) & 3; bx = bid & 127; bb = 0; }
    else { const int r = bid - 1024; z = 2; bb = r >> 5; by = (r >> 3) & 3; bx = r & 7; }

    const int row0 = bx * 128;
    const int n0   = by * 128;
    const float* __restrict__ A32 = isM1 ? (z ? k : q) : (v + (size_t)bb * DMODEL);
    const size_t astr = isM1 ? (size_t)DMODEL : (size_t)BATCH * DMODEL;
    const float* __restrict__ B32 = (z == 0) ? WQ : (z == 1) ? WK : WV;

    f32x4 acc[2][4] = {};

    // reg-stage roles (A and B identical): 16 rows/wave, row = wave*16+(lane>>2),
    // fp32 16B chunks c = (lane&3) + 4j, j=0..3 (64 cols = 16 chunks).
    const int srow = wave * 16 + (lane >> 2);
    const int sc0  = lane & 3;
    const float* __restrict__ aPtr = A32 + (size_t)(row0 + srow) * astr;
    const float* __restrict__ bPtr = B32 + (size_t)(n0 + srow) * DMODEL;

    float4 pA[4], pB[4];   // alternating fp32 A-tile register sets
    float4 wA[4], wB[4];   // alternating fp32 B-tile register sets

#define LOADA(kt, rg)                                                           \
    {                                                                           \
        _Pragma("unroll")                                                       \
        for (int j = 0; j < 4; j++)                                             \
            rg[j] = *(const float4*)(aPtr + (kt) + (sc0 + 4 * j) * 4);          \
    }
#define LOADB(kt, rg)                                                           \
    {                                                                           \
        _Pragma("unroll")                                                       \
        for (int j = 0; j < 4; j++)                                             \
            rg[j] = *(const float4*)(bPtr + (kt) + (sc0 + 4 * j) * 4);          \
    }
#define CVTWR(rg, lds, bufi)                                                    \
    {                                                                           \
        _Pragma("unroll")                                                       \
        for (int j = 0; j < 4; j++) {                                           \
            const int c = sc0 + 4 * j;                                          \
            u32 lo, hi;                                                         \
            asm("v_cvt_pk_bf16_f32 %0, %1, %2" : "=v"(lo) : "v"(rg[j].x), "v"(rg[j].y)); \
            asm("v_cvt_pk_bf16_f32 %0, %1, %2" : "=v"(hi) : "v"(rg[j].z), "v"(rg[j].w)); \
            uint2 pk; pk.x = lo; pk.y = hi;                                     \
            *(uint2*)&lds[bufi][srow * 64 + (((c >> 1) ^ (srow & 7)) << 3) +    \
                               ((c & 1) << 2)] = pk;                            \
        }                                                                       \
    }

    auto compute = [&](int bufi) {
        short8 af[2], bfr[4];
#pragma unroll
        for (int half = 0; half < 2; half++) {
#pragma unroll
            for (int mt = 0; mt < 2; mt++)
                af[mt] = *(const short8*)&Alds[bufi][(wm * 32 + mt * 16 + m16) * 64 +
                                                     (((half << 2) + quad) ^ (m16 & 7)) * 8];
#pragma unroll
            for (int nt = 0; nt < 4; nt++)
                bfr[nt] = *(const short8*)&Blds[bufi][(wn * 64 + nt * 16 + m16) * 64 +
                                                      (((half << 2) + quad) ^ (m16 & 7)) * 8];
            __builtin_amdgcn_s_setprio(1);
#pragma unroll
            for (int mt = 0; mt < 2; mt++)
#pragma unroll
                for (int nt = 0; nt < 4; nt++)
                    acc[mt][nt] = __builtin_amdgcn_mfma_f32_16x16x32_bf16(af[mt], bfr[nt], acc[mt][nt], 0, 0, 0);
            __builtin_amdgcn_s_setprio(0);
        }
    };

    // prologue: 2-deep prefetch. vmcnt events: A0(4) B0(4) A1(4) B1(4) = 16.
    LOADA(0, pA)
    LOADB(0, wA)
    LOADA(64, pB)
    LOADB(64, wB)
    asm volatile("s_waitcnt vmcnt(8)" ::: "memory");    // tile 0's A+B landed
    __builtin_amdgcn_sched_barrier(0);
    CVTWR(pA, Alds, 0)
    CVTWR(wA, Blds, 0)
    asm volatile("s_waitcnt lgkmcnt(0)" ::: "memory");
    __builtin_amdgcn_s_barrier();                        // buf 0 published
    __builtin_amdgcn_sched_barrier(0);

#pragma unroll
    for (int t = 0; t < 8; t++) {
        compute(t & 1);
        if (t < 6) {
            __builtin_amdgcn_s_barrier();               // readers done with buf t&1
            __builtin_amdgcn_sched_barrier(0);
            if (t & 1) { LOADA((t + 2) * 64, pB) LOADB((t + 2) * 64, wB) }
            else       { LOADA((t + 2) * 64, pA) LOADB((t + 2) * 64, wA) }
        }
        if (t < 7) {
            if (t < 6) asm volatile("s_waitcnt vmcnt(8)" ::: "memory");  // t+1 landed
            else       asm volatile("s_waitcnt vmcnt(0)" ::: "memory");
            __builtin_amdgcn_sched_barrier(0);
            if ((t + 1) & 1) { CVTWR(pB, Alds, 1) CVTWR(wB, Blds, 1) }
            else             { CVTWR(pA, Alds, 0) CVTWR(wA, Blds, 0) }
            asm volatile("s_waitcnt lgkmcnt(0)" ::: "memory");
            __builtin_amdgcn_s_barrier();               // buf (t+1)&1 published
            __builtin_amdgcn_sched_barrier(0);
        }
    }
#undef LOADA
#undef LOADB
#undef CVTWR

    // epilogue: per-head L2 norm + bf16 store
    const int h = (n0 >> 6) + wn;                       // head for this wave
    u16* outZ = outN + (size_t)z * ((size_t)BATCH * NHEAD * S_LEN * KHD);
    if (isM1) {
#pragma unroll
        for (int mt = 0; mt < 2; mt++) {
#pragma unroll
            for (int r = 0; r < 4; r++) {
                float ss = 0.0f;
#pragma unroll
                for (int nt = 0; nt < 4; nt++) ss += acc[mt][nt][r] * acc[mt][nt][r];
                ss += __shfl_xor(ss, 1);
                ss += __shfl_xor(ss, 2);
                ss += __shfl_xor(ss, 4);
                ss += __shfl_xor(ss, 8);
                const float sc = 1.0f / fmaxf(sqrtf(ss), 1e-12f);
                const int i = row0 + wm * 32 + mt * 16 + quad * 4 + r;
                const int s = i >> 4, bq = i & 15;
                u16* op = outZ + (((size_t)bq * NHEAD + h) * S_LEN + s) * KHD;
#pragma unroll
                for (int nt = 0; nt < 4; nt++)
                    op[nt * 16 + m16] = f2bf(acc[mt][nt][r] * sc);
            }
        }
    } else {
#pragma unroll
        for (int mt = 0; mt < 2; mt++) {
            float scl[4];
#pragma unroll
            for (int r = 0; r < 4; r++) {
                float ss = 0.0f;
#pragma unroll
                for (int nt = 0; nt < 4; nt++) ss += acc[mt][nt][r] * acc[mt][nt][r];
                ss += __shfl_xor(ss, 1);
                ss += __shfl_xor(ss, 2);
                ss += __shfl_xor(ss, 4);
                ss += __shfl_xor(ss, 8);
                scl[r] = 1.0f / fmaxf(sqrtf(ss), 1e-12f);
            }
            const int sbase = row0 + wm * 32 + mt * 16 + quad * 4;
#pragma unroll
            for (int nt = 0; nt < 4; nt++) {
                const int vcol = nt * 16 + m16;
                uint2 pk;
                pk.x = (u32)f2bf(acc[mt][nt][0] * scl[0]) |
                       ((u32)f2bf(acc[mt][nt][1] * scl[1]) << 16);
                pk.y = (u32)f2bf(acc[mt][nt][2] * scl[2]) |
                       ((u32)f2bf(acc[mt][nt][3] * scl[3]) << 16);
                u16* dp = outZ + (((size_t)bb * NHEAD + h) * KHD + vcol) * S_LEN + sbase;
                *(uint2*)dp = pk;
            }
        }
    }
}

// ---------------------------------------------------------------------------
// Output projection v2: R7 counted-vmcnt skeleton; B now staged from fp32
// Wout via reg-cvt (wcvt dead). A gathered bf16 from [B][H][S][64] via
// global_load_lds (2/wave). Stage = A2 + B4 = 6 vmem -> vmcnt(6).
// T5 setprio around MFMA. fp32 out. grid (128,4) x 512 threads.
// ---------------------------------------------------------------------------
__global__ __launch_bounds__(512, 4) void gemm_out_kernel(
    const u16* __restrict__ Abf,      // bf16 A, [B][H][S][64]
    const float* __restrict__ Wo32,   // fp32 Wout [512][512]
    float* __restrict__ outP)
{
    __shared__ __align__(16) u16 Alds[2][128 * 64];
    __shared__ __align__(16) u16 Blds[2][128 * 64];

    const int tid  = threadIdx.x;
    const int wave = tid >> 6;          // 0..7
    const int lane = tid & 63;
    const int m16  = lane & 15;
    const int quad = lane >> 4;
    const int wm   = wave >> 1;         // 0..3: 32-row group
    const int wn   = wave & 1;          // 0..1: 64-col half
    const int n0   = blockIdx.y * 128;
    const int row0 = blockIdx.x * 128;

    const int brow   = lane >> 3;              // 0..7
    const int bchunk = (lane & 7) ^ brow;      // XOR chunk swizzle (A gather)
    // B reg-stage roles: row = wave*16+(lane>>2), fp32 16B chunk c = (lane&3)+4j
    const int srow = wave * 16 + (lane >> 2);
    const int sc0  = lane & 3;
    const float* __restrict__ bPtr = Wo32 + (size_t)(n0 + srow) * DMODEL;

    f32x4 acc[2][4] = {};
    float4 wA[4], wB[4];

    auto stageA = [&](int kt, int b) {
        const int colc = kt + bchunk * 8;
        const int hh   = colc >> 6;
        const int kk   = colc & 63;
        u16* la = &Alds[b][(wave * 16) * 64];
#pragma unroll
        for (int j = 0; j < 2; j++) {
            const int i  = row0 + wave * 16 + j * 8 + brow;
            const int ss = i >> 4, bx = i & 15;
            gl_lds16(Abf + (((size_t)(bx * NHEAD + hh) * S_LEN + ss) * KHD + kk),
                     la + j * 8 * 64);
        }
    };
#define LOADB(kt, rg)                                                           \
    {                                                                           \
        _Pragma("unroll")                                                       \
        for (int j = 0; j < 4; j++)                                             \
            rg[j] = *(const float4*)(bPtr + (kt) + (sc0 + 4 * j) * 4);          \
    }
#define CVTWRB(rg, bufi)                                                        \
    {                                                                           \
        _Pragma("unroll")                                                       \
        for (int j = 0; j < 4; j++) {                                           \
            const int c = sc0 + 4 * j;                                          \
            u32 lo, hi;                                                         \
            asm("v_cvt_pk_bf16_f32 %0, %1, %2" : "=v"(lo) : "v"(rg[j].x), "v"(rg[j].y)); \
            asm("v_cvt_pk_bf16_f32 %0, %1, %2" : "=v"(hi) : "v"(rg[j].z), "v"(rg[j].w)); \
            uint2 pk; pk.x = lo; pk.y = hi;                                     \
            *(uint2*)&Blds[bufi][srow * 64 + (((c >> 1) ^ (srow & 7)) << 3) +   \
                                 ((c & 1) << 2)] = pk;                          \
        }                                                                       \
    }
    auto compute = [&](int b) {
        short8 af[2], bfr[4];
#pragma unroll
        for (int half = 0; half < 2; half++) {
#pragma unroll
            for (int mt = 0; mt < 2; mt++)
                af[mt] = *(const short8*)&Alds[b][(wm * 32 + mt * 16 + m16) * 64 +
                                                  (((half << 2) + quad) ^ (m16 & 7)) * 8];
#pragma unroll
            for (int nt = 0; nt < 4; nt++)
                bfr[nt] = *(const short8*)&Blds[b][(wn * 64 + nt * 16 + m16) * 64 +
                                                   (((half << 2) + quad) ^ (m16 & 7)) * 8];
            __builtin_amdgcn_s_setprio(1);
#pragma unroll
            for (int mt = 0; mt < 2; mt++)
#pragma unroll
                for (int nt = 0; nt < 4; nt++)
                    acc[mt][nt] = __builtin_amdgcn_mfma_f32_16x16x32_bf16(af[mt], bfr[nt], acc[mt][nt], 0, 0, 0);
            __builtin_amdgcn_s_setprio(0);
        }
    };

    // prologue: A0(2) B0(4) A1(2) B1(4) = 12 outstanding; wait first 6.
    stageA(0, 0);
    LOADB(0, wA)
    stageA(64, 1);
    LOADB(64, wB)
    asm volatile("s_waitcnt vmcnt(6)" ::: "memory");
    __builtin_amdgcn_sched_barrier(0);
    CVTWRB(wA, 0)
    asm volatile("s_waitcnt lgkmcnt(0)" ::: "memory");
    __builtin_amdgcn_s_barrier();
    __builtin_amdgcn_sched_barrier(0);

#pragma unroll
    for (int t = 0; t < 8; t++) {
        compute(t & 1);
        if (t < 6) {
            __builtin_amdgcn_s_barrier();
            __builtin_amdgcn_sched_barrier(0);
            stageA((t + 2) * 64, t & 1);
            if (t & 1) { LOADB((t + 2) * 64, wB) }
            else       { LOADB((t + 2) * 64, wA) }
        }
        if (t < 7) {
            if (t < 6) asm volatile("s_waitcnt vmcnt(6)" ::: "memory");
            else       asm volatile("s_waitcnt vmcnt(0)" ::: "memory");
            __builtin_amdgcn_sched_barrier(0);
            if ((t + 1) & 1) { CVTWRB(wB, 1) }
            else             { CVTWRB(wA, 0) }
            asm volatile("s_waitcnt lgkmcnt(0)" ::: "memory");
            __builtin_amdgcn_s_barrier();
            __builtin_amdgcn_sched_barrier(0);
        }
    }
#undef LOADB
#undef CVTWRB

    // epilogue: fp32 C write
#pragma unroll
    for (int mt = 0; mt < 2; mt++) {
#pragma unroll
        for (int r = 0; r < 4; r++) {
            const int i = row0 + wm * 32 + mt * 16 + quad * 4 + r;
            float* op = outP + (size_t)i * DMODEL + n0 + wn * 64;
#pragma unroll
            for (int nt = 0; nt < 4; nt++)
                op[nt * 16 + m16] = acc[mt][nt][r];
        }
    }
}

// ---------------------------------------------------------------------------
// Attention v6 (best measured). 256 q/block (64 per wave, qb=0..3), 64-key
// iters, grid (128,4): blockIdx.x = bh -> all q-tiles of one head on ONE XCD;
// per-XCD K/V = 16 heads x 256KB = 4MB = L2. Double-buffered K/V. P staged
// per 32-key half in per-wave-per-qb [16q][32k] buffers. LDS = 48KB.
// Plds swizzle: 64B rows, 16B chunk ^= (m16>>1)&3 -> conflict-free b128.
// Scores = cos/8; p = exp(y/8) via quadratic Taylor; truncate-pack via
// v_perm; row-sum via ones-MFMA on packed P (exact num/denom consistency).
// Output written DIRECTLY into the wq region in [B][H][S][64] layout.
// ---------------------------------------------------------------------------
__global__ __launch_bounds__(256, 2) void attn_kernel(
    const u16* __restrict__ wq, const u16* __restrict__ wk, const u16* __restrict__ wvT,
    u16* __restrict__ Xout)     // = wq base, [B][H][S][64]
{
    __shared__ __align__(16) u16 Klds[2][64 * 64];    // [buf][key][dim], XOR chunks
    __shared__ __align__(16) u16 Vlds[2][64 * 64];    // [buf][vcol][key], XOR chunks
    __shared__ __align__(16) u16 Plds[4][4][16 * 32]; // [wave][qb][q16][key32], XOR chunks

    const int tid  = threadIdx.x;
    const int wave = tid >> 6;
    const int lane = tid & 63;
    const int m16  = lane & 15;
    const int quad = lane >> 4;
    const int bh   = blockIdx.x;        // 0..127  (XCD = bh % 8)
    const int qt   = blockIdx.y;        // 4 tiles of 256 q

    const u16* Qb = wq  + (size_t)bh * S_LEN * KHD;
    const u16* Kb = wk  + (size_t)bh * S_LEN * KHD;
    const u16* Vb = wvT + (size_t)bh * KHD * S_LEN;

    // 64 q rows per wave: row = qr0 + qb*16 + m16
    const int qr0 = qt * 256 + wave * 64;
    short8 qf[4][2];
#pragma unroll
    for (int qb = 0; qb < 4; qb++) {
        qf[qb][0] = *(const short8*)(Qb + (size_t)(qr0 + qb * 16 + m16) * KHD + quad * 8);
        qf[qb][1] = *(const short8*)(Qb + (size_t)(qr0 + qb * 16 + m16) * KHD + 32 + quad * 8);
    }

    short8 ones;
#pragma unroll
    for (int j = 0; j < 8; j++) ones[j] = (short)0x3F80;   // bf16 1.0

    f32x4 o[4][4] = {};   // [qb][vt]: D[m=vcol][n=q]
    f32x4 ls[4]   = {};   // [qb] ones-MFMA row-sum accumulator
    const float C1 = 0.125f, C2 = 0.0078125f;   // exp(y/8) ~= 1 + y/8 + y^2/128

    const int srow   = lane >> 3;
    const int schunk = (lane & 7) ^ srow;
    const int r0     = wave * 8 + srow;
    const int pswz   = (m16 >> 1) & 3;          // Plds chunk XOR

    // prologue: stage tile 0 into buf 0
    gl_lds16(Kb + (size_t)r0 * KHD + schunk * 8,               &Klds[0][(wave * 8) * 64]);
    gl_lds16(Kb + (size_t)(r0 + 32) * KHD + schunk * 8,        &Klds[0][(wave * 8 + 32) * 64]);
    gl_lds16(Vb + (size_t)r0 * S_LEN + schunk * 8,             &Vlds[0][(wave * 8) * 64]);
    gl_lds16(Vb + (size_t)(r0 + 32) * S_LEN + schunk * 8,      &Vlds[0][(wave * 8 + 32) * 64]);
    __syncthreads();

    for (int it = 0; it < S_LEN / 64; it++) {
        const int cur = it & 1;

        // stage NEXT tile into the other buffer; latency hides under compute
        if (it + 1 < S_LEN / 64) {
            const int nxt = cur ^ 1;
            const int kt0 = (it + 1) * 64;
            gl_lds16(Kb + (size_t)(kt0 + r0) * KHD + schunk * 8,        &Klds[nxt][(wave * 8) * 64]);
            gl_lds16(Kb + (size_t)(kt0 + r0 + 32) * KHD + schunk * 8,   &Klds[nxt][(wave * 8 + 32) * 64]);
            gl_lds16(Vb + (size_t)r0 * S_LEN + kt0 + schunk * 8,        &Vlds[nxt][(wave * 8) * 64]);
            gl_lds16(Vb + (size_t)(r0 + 32) * S_LEN + kt0 + schunk * 8, &Vlds[nxt][(wave * 8 + 32) * 64]);
        }

#pragma unroll
        for (int cc = 0; cc < 2; cc++) {
            // S^T for keys cc*32..cc*32+31: D[m=key][n=q] = K x Q^T
#pragma unroll
            for (int mm = 0; mm < 2; mm++) {
                const int mt = cc * 2 + mm;
                const short8 kf0 = *(const short8*)&Klds[cur][(mt * 16 + m16) * 64 + (quad ^ (m16 & 7)) * 8];
                const short8 kf1 = *(const short8*)&Klds[cur][(mt * 16 + m16) * 64 + ((4 + quad) ^ (m16 & 7)) * 8];
#pragma unroll
                for (int qb = 0; qb < 4; qb++) {
                    f32x4 s = {};
                    s = __builtin_amdgcn_mfma_f32_16x16x32_bf16(kf0, qf[qb][0], s, 0, 0, 0);
                    s = __builtin_amdgcn_mfma_f32_16x16x32_bf16(kf1, qf[qb][1], s, 0, 0, 0);
                    u32 up[4];
#pragma unroll
                    for (int r = 0; r < 4; r++) {
                        const float y = s[r];
                        const float p = fmaf(fmaf(C2, y, C1), y, 1.0f);
                        up[r] = __float_as_uint(p);
                    }
                    uint2 pk;   // truncation-pack two bf16 per u32 via byte-perm
                    pk.x = __builtin_amdgcn_perm(up[1], up[0], 0x07060302u);
                    pk.y = __builtin_amdgcn_perm(up[3], up[2], 0x07060302u);
                    // logical: row m16 (64B), chunk = mm*2 + quad>>1, half = quad&1
                    *(uint2*)((char*)&Plds[wave][qb][0] + m16 * 64 +
                              ((((mm << 1) + (quad >> 1)) ^ pswz) << 4) + ((quad & 1) << 3)) = pk;
                }
            }

            // PV for this 32-key half + ones-MFMA row-sum (wave-private P)
            short8 vfr[4];
#pragma unroll
            for (int vt = 0; vt < 4; vt++)
                vfr[vt] = *(const short8*)&Vlds[cur][(vt * 16 + m16) * 64 +
                                                     (((cc << 2) + quad) ^ (m16 & 7)) * 8];
            __builtin_amdgcn_s_setprio(1);
#pragma unroll
            for (int qb = 0; qb < 4; qb++) {
                const short8 pb = *(const short8*)((const char*)&Plds[wave][qb][0] + m16 * 64 +
                                                   ((quad ^ pswz) << 4));
                ls[qb] = __builtin_amdgcn_mfma_f32_16x16x32_bf16(ones, pb, ls[qb], 0, 0, 0);
#pragma unroll
                for (int vt = 0; vt < 4; vt++)
                    o[qb][vt] = __builtin_amdgcn_mfma_f32_16x16x32_bf16(vfr[vt], pb, o[qb][vt], 0, 0, 0);
            }
            __builtin_amdgcn_s_setprio(0);
        }

        __syncthreads();   // drains vmcnt (next tile visible) + frees cur buf
    }

    // epilogue: lane's q = m16; write into wq region, [B][H][S][64] layout.
    u16* outB = Xout + (size_t)bh * S_LEN * KHD;
#pragma unroll
    for (int qb = 0; qb < 4; qb++) {
        const float inv = 1.0f / ls[qb][0];
        const int qrow = qr0 + qb * 16 + m16;
        u16* cp = outB + (size_t)qrow * KHD;
#pragma unroll
        for (int vt = 0; vt < 4; vt++) {
            uint2 pk;
            pk.x = (u32)f2bf(o[qb][vt][0] * inv) | ((u32)f2bf(o[qb][vt][1] * inv) << 16);
            pk.y = (u32)f2bf(o[qb][vt][2] * inv) | ((u32)f2bf(o[qb][vt][3] * inv) << 16);
            *(uint2*)(cp + vt * 16 + quad * 4) = pk;
        }
    }
}

extern "C" void kernel_launch(void* const* d_in, const int* in_sizes, int n_in,
                              void* d_out, int out_size, void* d_ws, size_t ws_size,
                              hipStream_t stream) {
    const float* q    = (const float*)d_in[0];
    const float* k    = (const float*)d_in[1];
    const float* v    = (const float*)d_in[2];
    const float* WQ   = (const float*)d_in[3];
    const float* WK   = (const float*)d_in[4];
    const float* WV   = (const float*)d_in[5];
    const float* Wout = (const float*)d_in[6];
    float* out = (float*)d_out;

    // ws: [3][B*H*S*64] bf16 (wq, wk, wvT) = 50.3 MB (weights read fp32 direct)
    const size_t per = (size_t)BATCH * NHEAD * S_LEN * KHD;
    u16* wsQKV = (u16*)d_ws;

    // 1. q,k,v projections + norm, ONE dispatch; B converted in-kernel
    proj_kernel<<<dim3(1536), 512, 0, stream>>>(q, k, v, WQ, WK, WV, wsQKV);

    // 2. attention -> concat written in-place into the wq region
    //    ([B][H][S][64]); each block touches only its own slice -> no race
    attn_kernel<<<dim3(BATCH * NHEAD, S_LEN / 256), 256, 0, stream>>>(
        wsQKV, wsQKV + per, wsQKV + 2 * per, wsQKV);

    // 3. output projection (counted-vmcnt; Wout converted in-kernel) -> fp32
    gemm_out_kernel<<<dim3(NROW / 128, DMODEL / 128), 512, 0, stream>>>(
        wsQKV, Wout, out);
}